// Round 1
// baseline (791.944 us; speedup 1.0000x reference)
//
#include <hip/hip_runtime.h>

// GAT encoder: B=16, N=768, IN=16, HID=64, HEADS=8, EMB=128, 2 GAT layers.
// Round 0: correct fp32 baseline, fused softmax+PV (no 302MB att tensor).
// ws layout (floats): h0[B*N*64] | Wh[B*8*N*64] | s1[B*8*N] | s2[B*8*N] | hp[B*N*512]
// total ~52 MB.

#define B_ 16
#define N_ 768
#define IN_DIM_ 16
#define HID_ 64
#define EMB_ 128
#define NH_ 8
#define F1_ (NH_ * HID_) // 512

// ---------------- input projection: h0 = x @ ip_w + ip_b ----------------
__global__ __launch_bounds__(256) void k_inproj(const float* __restrict__ x,
                                                const float* __restrict__ w,
                                                const float* __restrict__ bias,
                                                float* __restrict__ h0) {
    int g = blockIdx.x * 256 + threadIdx.x;       // B*N*HID threads
    int o = g & (HID_ - 1);
    int row = g >> 6;                             // b*N + n (wave-uniform)
    const float* xr = x + row * IN_DIM_;
    float acc = bias[o];
#pragma unroll
    for (int f = 0; f < IN_DIM_; ++f) acc = fmaf(xr[f], w[f * HID_ + o], acc);
    h0[row * HID_ + o] = acc;
}

// -------- Wh GEMM + fused s1/s2: Wh[b,h,n,o] = sum_f h[b,n,f]*W[h,f,o] --------
// block = 256 threads, handles (b, h, 16 rows of n). o = tid&63, ng = tid>>6.
template <int F>
__global__ __launch_bounds__(256) void k_wh(const float* __restrict__ hin,
                                            const float* __restrict__ W,
                                            const float* __restrict__ a,
                                            float* __restrict__ Wh,
                                            float* __restrict__ s1,
                                            float* __restrict__ s2) {
    __shared__ __align__(16) float hs[16 * F];
    const int bid = blockIdx.x;
    const int n0 = (bid % (N_ / 16)) * 16;
    const int h = (bid / (N_ / 16)) % NH_;
    const int b = bid / ((N_ / 16) * NH_);

    const float4* hb = (const float4*)(hin + (b * N_ + n0) * F);
    float4* hs4 = (float4*)hs;
    for (int i = threadIdx.x; i < 16 * F / 4; i += 256) hs4[i] = hb[i];
    __syncthreads();

    const int o = threadIdx.x & 63;
    const int ng = threadIdx.x >> 6;
    float acc[4] = {0.f, 0.f, 0.f, 0.f};
    const float* Wp = W + h * F * HID_ + o;
    for (int f = 0; f < F; f += 4) {
        float wv0 = Wp[(f + 0) * HID_];
        float wv1 = Wp[(f + 1) * HID_];
        float wv2 = Wp[(f + 2) * HID_];
        float wv3 = Wp[(f + 3) * HID_];
#pragma unroll
        for (int k = 0; k < 4; ++k) {
            float4 hv = *(const float4*)&hs[(ng + 4 * k) * F + f];
            float t = acc[k];
            t = fmaf(hv.x, wv0, t);
            t = fmaf(hv.y, wv1, t);
            t = fmaf(hv.z, wv2, t);
            t = fmaf(hv.w, wv3, t);
            acc[k] = t;
        }
    }

    const float a1v = a[h * 2 * HID_ + o];
    const float a2v = a[h * 2 * HID_ + HID_ + o];
    float* Whb = Wh + ((b * NH_ + h) * N_ + n0) * HID_;
    float* s1b = s1 + (b * NH_ + h) * N_ + n0;
    float* s2b = s2 + (b * NH_ + h) * N_ + n0;
#pragma unroll
    for (int k = 0; k < 4; ++k) {
        int r = ng + 4 * k;
        Whb[r * HID_ + o] = acc[k];
        float r1 = acc[k] * a1v;
        float r2 = acc[k] * a2v;
#pragma unroll
        for (int off = 32; off; off >>= 1) {
            r1 += __shfl_xor(r1, off);
            r2 += __shfl_xor(r2, off);
        }
        if (o == 0) {
            s1b[r] = r1;
            s2b[r] = r2;
        }
    }
}

// ---- fused attention: att = softmax(leaky_relu(s1[n]+s2[m])); hp = att @ Wh ----
// block = 256 threads (4 waves), handles (b, h, 16 rows). Wave w owns rows {w,w+4,w+8,w+12}.
__global__ __launch_bounds__(256) void k_attn(const float* __restrict__ Wh,
                                              const float* __restrict__ s1,
                                              const float* __restrict__ s2,
                                              float* __restrict__ hp) {
    __shared__ __align__(16) float s2s[N_];
    __shared__ __align__(16) float p[16][N_];
    const int bid = blockIdx.x;
    const int n0 = (bid % (N_ / 16)) * 16;
    const int h = (bid / (N_ / 16)) % NH_;
    const int b = bid / ((N_ / 16) * NH_);

    const float* s2g = s2 + (b * NH_ + h) * N_;
    for (int i = threadIdx.x; i < N_; i += 256) s2s[i] = s2g[i];
    __syncthreads();

    const int lane = threadIdx.x & 63;
    const int w = threadIdx.x >> 6;
    const float* s1b = s1 + (b * NH_ + h) * N_ + n0;

#pragma unroll
    for (int j = 0; j < 4; ++j) {
        const int r = w + 4 * j;
        const float s1v = s1b[r];
        float v[12];
        float mx = -3.0e38f;
#pragma unroll
        for (int i = 0; i < 12; ++i) {
            float e = s1v + s2s[lane + 64 * i];
            e = (e >= 0.f) ? e : 0.2f * e;   // leaky_relu(slope 0.2)
            v[i] = e;
            mx = fmaxf(mx, e);
        }
#pragma unroll
        for (int off = 32; off; off >>= 1) mx = fmaxf(mx, __shfl_xor(mx, off));
        float sum = 0.f;
#pragma unroll
        for (int i = 0; i < 12; ++i) {
            v[i] = __expf(v[i] - mx);
            sum += v[i];
        }
#pragma unroll
        for (int off = 32; off; off >>= 1) sum += __shfl_xor(sum, off);
        const float inv = 1.f / sum;
#pragma unroll
        for (int i = 0; i < 12; ++i) p[r][lane + 64 * i] = v[i] * inv;
    }
    __syncthreads();

    // PV: hp[r][o] = sum_m p[r][m] * Wh[m][o]; thread = (w, o=lane), 4 rows each.
    const int o = lane;
    float acc[4] = {0.f, 0.f, 0.f, 0.f};
    const float* Whb = Wh + (b * NH_ + h) * N_ * HID_ + o;
    for (int m = 0; m < N_; m += 4) {
        float w0 = Whb[(m + 0) * HID_];
        float w1 = Whb[(m + 1) * HID_];
        float w2 = Whb[(m + 2) * HID_];
        float w3 = Whb[(m + 3) * HID_];
#pragma unroll
        for (int j = 0; j < 4; ++j) {
            float4 pv = *(const float4*)&p[w + 4 * j][m];
            float t = acc[j];
            t = fmaf(pv.x, w0, t);
            t = fmaf(pv.y, w1, t);
            t = fmaf(pv.z, w2, t);
            t = fmaf(pv.w, w3, t);
            acc[j] = t;
        }
    }
    // write into (B,N,512) layout: [b, n, h*64+o]
    float* hpb = hp + (b * N_ + n0) * F1_ + h * HID_ + o;
#pragma unroll
    for (int j = 0; j < 4; ++j) hpb[(w + 4 * j) * F1_] = acc[j];
}

// ---------------- output projection: out = hp @ proj_w + proj_b ----------------
__global__ __launch_bounds__(256) void k_proj(const float* __restrict__ hin,
                                              const float* __restrict__ W,
                                              const float* __restrict__ bias,
                                              float* __restrict__ out) {
    __shared__ __align__(16) float hs[16 * F1_];
    const int n0 = blockIdx.x * 16;  // rows over B*N
    const float4* hb = (const float4*)(hin + n0 * F1_);
    float4* hs4 = (float4*)hs;
    for (int i = threadIdx.x; i < 16 * F1_ / 4; i += 256) hs4[i] = hb[i];
    __syncthreads();

    const int o = threadIdx.x & 127;
    const int ng = threadIdx.x >> 7;  // 0..1
    float acc[8] = {0.f, 0.f, 0.f, 0.f, 0.f, 0.f, 0.f, 0.f};
    for (int f = 0; f < F1_; f += 4) {
        float wv0 = W[(f + 0) * EMB_ + o];
        float wv1 = W[(f + 1) * EMB_ + o];
        float wv2 = W[(f + 2) * EMB_ + o];
        float wv3 = W[(f + 3) * EMB_ + o];
#pragma unroll
        for (int k = 0; k < 8; ++k) {
            float4 hv = *(const float4*)&hs[(ng + 2 * k) * F1_ + f];
            float t = acc[k];
            t = fmaf(hv.x, wv0, t);
            t = fmaf(hv.y, wv1, t);
            t = fmaf(hv.z, wv2, t);
            t = fmaf(hv.w, wv3, t);
            acc[k] = t;
        }
    }
    const float bv = bias[o];
#pragma unroll
    for (int k = 0; k < 8; ++k) out[(n0 + ng + 2 * k) * EMB_ + o] = acc[k] + bv;
}

extern "C" void kernel_launch(void* const* d_in, const int* in_sizes, int n_in,
                              void* d_out, int out_size, void* d_ws, size_t ws_size,
                              hipStream_t stream) {
    const float* x    = (const float*)d_in[0];
    const float* ip_w = (const float*)d_in[1];
    const float* ip_b = (const float*)d_in[2];
    const float* gw0  = (const float*)d_in[3];
    const float* ga0  = (const float*)d_in[4];
    const float* gw1  = (const float*)d_in[5];
    const float* ga1  = (const float*)d_in[6];
    const float* pw   = (const float*)d_in[7];
    const float* pb   = (const float*)d_in[8];
    float* out = (float*)d_out;

    float* ws = (float*)d_ws;
    float* h0 = ws;                      // B*N*HID        = 786432 f
    float* Wh = h0 + B_ * N_ * HID_;     // B*NH*N*HID     = 6291456 f
    float* s1 = Wh + B_ * NH_ * N_ * HID_;  // B*NH*N      = 98304 f
    float* s2 = s1 + B_ * NH_ * N_;
    float* hp = s2 + B_ * NH_ * N_;      // B*N*512        = 6291456 f
    // total ~13.57M floats ~= 52 MB of d_ws

    const int gat_blocks = B_ * NH_ * (N_ / 16);  // 6144

    k_inproj<<<B_ * N_ * HID_ / 256, 256, 0, stream>>>(x, ip_w, ip_b, h0);
    k_wh<HID_><<<gat_blocks, 256, 0, stream>>>(h0, gw0, ga0, Wh, s1, s2);
    k_attn<<<gat_blocks, 256, 0, stream>>>(Wh, s1, s2, hp);
    k_wh<F1_><<<gat_blocks, 256, 0, stream>>>(hp, gw1, ga1, Wh, s1, s2);
    k_attn<<<gat_blocks, 256, 0, stream>>>(Wh, s1, s2, hp);   // overwrites hp (reads only Wh/s1/s2)
    k_proj<<<(B_ * N_) / 16, 256, 0, stream>>>(hp, pw, pb, out);
}

// Round 2
// 443.819 us; speedup vs baseline: 1.7844x; 1.7844x over previous
//
#include <hip/hip_runtime.h>
#include <hip/hip_bf16.h>

// GAT encoder: B=16, N=768, IN=16, HID=64, HEADS=8, EMB=128, 2 GAT layers.
// Round 1: MFMA-based fused attention (PV on matrix cores, ones-column denom),
// k_wh restructured to emit Wh as bf16 MFMA B-fragments.
// ws (floats): h0[786432] | Whf(bf16)[6291456 us = 3145728 f] | s1[98304] | s2[98304] | hp[6291456]

#define B_ 16
#define N_ 768
#define IN_DIM_ 16
#define HID_ 64
#define EMB_ 128
#define NH_ 8
#define F1_ (NH_ * HID_) // 512
#define LOG2E_ 1.4426950408889634f

typedef __attribute__((ext_vector_type(4))) float f32x4;
typedef __attribute__((ext_vector_type(8))) short bf16x8;

static __device__ __forceinline__ short f2bf(float x) {
    __hip_bfloat16 b = __float2bfloat16(x);
    return *reinterpret_cast<short*>(&b);
}

// ---------------- input projection: h0 = x @ ip_w + ip_b ----------------
__global__ __launch_bounds__(256) void k_inproj(const float* __restrict__ x,
                                                const float* __restrict__ w,
                                                const float* __restrict__ bias,
                                                float* __restrict__ h0) {
    int g = blockIdx.x * 256 + threadIdx.x;       // B*N*HID threads
    int o = g & (HID_ - 1);
    int row = g >> 6;                             // b*N + n (wave-uniform)
    const float* xr = x + row * IN_DIM_;
    float acc = bias[o];
#pragma unroll
    for (int f = 0; f < IN_DIM_; ++f) acc = fmaf(xr[f], w[f * HID_ + o], acc);
    h0[row * HID_ + o] = acc;
}

// -------- Wh GEMM + fused s1/s2 + bf16-fragment output --------
// 32 rows per block (one MFMA K-step of the consumer). 256 thr: o=tid&63, ng=tid>>6,
// thread computes rows r = ng*8 + k (k=0..7).
// Whf fragment layout: [b,h][kt=row/32][nt=o>>4][lane'][j] where
//   lane' = (r>>3)*16 + (o&15) (B-operand: col=l&15, k=(l>>4)*8+j), j = r&7.
template <int F>
__global__ __launch_bounds__(256) void k_wh(const float* __restrict__ hin,
                                            const float* __restrict__ W,
                                            const float* __restrict__ a,
                                            ushort* __restrict__ Whf,
                                            float* __restrict__ s1,
                                            float* __restrict__ s2) {
    __shared__ __align__(16) float hs[32 * F];
    __shared__ __align__(16) ushort fb[2048];
    const int bid = blockIdx.x;
    const int kt = bid % (N_ / 32);
    const int h = (bid / (N_ / 32)) % NH_;
    const int b = bid / ((N_ / 32) * NH_);
    const int n0 = kt * 32;

    const float4* hb = (const float4*)(hin + (b * N_ + n0) * F);
    float4* hs4 = (float4*)hs;
    for (int i = threadIdx.x; i < 32 * F / 4; i += 256) hs4[i] = hb[i];
    __syncthreads();

    const int o = threadIdx.x & 63;
    const int ng = threadIdx.x >> 6;
    float acc[8] = {0.f, 0.f, 0.f, 0.f, 0.f, 0.f, 0.f, 0.f};
    const float* Wp = W + h * F * HID_ + o;
    for (int f = 0; f < F; f += 4) {
        float wv0 = Wp[(f + 0) * HID_];
        float wv1 = Wp[(f + 1) * HID_];
        float wv2 = Wp[(f + 2) * HID_];
        float wv3 = Wp[(f + 3) * HID_];
#pragma unroll
        for (int k = 0; k < 8; ++k) {
            float4 hv = *(const float4*)&hs[(ng * 8 + k) * F + f];
            float t = acc[k];
            t = fmaf(hv.x, wv0, t);
            t = fmaf(hv.y, wv1, t);
            t = fmaf(hv.z, wv2, t);
            t = fmaf(hv.w, wv3, t);
            acc[k] = t;
        }
    }

    // fused s1/s2 (fp32)
    const float a1v = a[h * 2 * HID_ + o];
    const float a2v = a[h * 2 * HID_ + HID_ + o];
    float* s1b = s1 + (b * NH_ + h) * N_ + n0;
    float* s2b = s2 + (b * NH_ + h) * N_ + n0;
#pragma unroll
    for (int k = 0; k < 8; ++k) {
        float r1 = acc[k] * a1v;
        float r2 = acc[k] * a2v;
#pragma unroll
        for (int off = 32; off; off >>= 1) {
            r1 += __shfl_xor(r1, off);
            r2 += __shfl_xor(r2, off);
        }
        if (o == 0) {
            s1b[ng * 8 + k] = r1;
            s2b[ng * 8 + k] = r2;
        }
    }

    // pack Wh tile into bf16 B-fragments via LDS transpose buffer
    bf16x8 pk;
#pragma unroll
    for (int k = 0; k < 8; ++k) pk[k] = f2bf(acc[k]);
    *(bf16x8*)&fb[(((o >> 4) * 64) + ng * 16 + (o & 15)) * 8] = pk;
    __syncthreads();

    bf16x8 v = *(const bf16x8*)&fb[threadIdx.x * 8];
    *(bf16x8*)&Whf[((b * NH_ + h) * (N_ / 32) + kt) * 2048 + threadIdx.x * 8] = v;
}

// ---- fused attention on MFMA: p = softmax(LR(s1[n]+s2[m])); hp = p @ Wh ----
// Grid: (b,h,128-row chunk) = 768 blocks, 4 waves; wave w owns rows [w*32, w*32+32).
// A-fragments (p-tilde) generated in-register (exp2); denominator via ones-column MFMA.
__global__ __launch_bounds__(256) void k_attn(const ushort* __restrict__ Whf,
                                              const float* __restrict__ s1,
                                              const float* __restrict__ s2,
                                              float* __restrict__ hp) {
    __shared__ __align__(16) float t1s[128];
    __shared__ __align__(16) float t2s[N_];
    __shared__ __align__(16) float dls[128];
    const int bid = blockIdx.x;
    const int nc = bid % (N_ / 128);
    const int h = (bid / (N_ / 128)) % NH_;
    const int b = bid / ((N_ / 128) * NH_);
    const int n0 = nc * 128;
    const int bh = b * NH_ + h;

    const float* s1g = s1 + bh * N_;
    const float* s2g = s2 + bh * N_;
    for (int i = threadIdx.x; i < N_; i += 256) t2s[i] = s2g[i] * LOG2E_;
    if (threadIdx.x < 128) t1s[threadIdx.x] = s1g[n0 + threadIdx.x] * LOG2E_;
    __syncthreads();

    const int lane = threadIdx.x & 63;
    const int w = threadIdx.x >> 6;
    const int rowbase = w * 32;
    const int lg = lane >> 4;      // k-group 0..3
    const int ll = lane & 15;      // col / row-in-tile

    const float t1a = t1s[rowbase + ll];
    const float t1b = t1s[rowbase + 16 + ll];

    f32x4 zero4 = {0.f, 0.f, 0.f, 0.f};
    f32x4 acc[2][4];
    f32x4 dacc[2];
#pragma unroll
    for (int mt = 0; mt < 2; ++mt) {
        dacc[mt] = zero4;
#pragma unroll
        for (int nt = 0; nt < 4; ++nt) acc[mt][nt] = zero4;
    }

    bf16x8 onesB;
#pragma unroll
    for (int j = 0; j < 8; ++j) onesB[j] = (ll == 0) ? (short)0x3F80 : (short)0;

    const ushort* Wbase = Whf + bh * ((N_ / 32) * 2048);

    for (int ktile = 0; ktile < N_ / 32; ++ktile) {
        // B fragments: 4 N-tiles, contiguous 16B per lane
        bf16x8 bq[4];
        const ushort* p = Wbase + ktile * 2048 + lane * 8;
#pragma unroll
        for (int nt = 0; nt < 4; ++nt) bq[nt] = *(const bf16x8*)(p + nt * 512);

        // scores for this K-step (log2-scaled)
        float qv[8];
        const float* q = &t2s[ktile * 32 + lg * 8];
#pragma unroll
        for (int j = 0; j < 8; ++j) qv[j] = q[j];

#pragma unroll
        for (int mt = 0; mt < 2; ++mt) {
            const float t1v = mt ? t1b : t1a;
            bf16x8 af;
#pragma unroll
            for (int j = 0; j < 8; ++j) {
                float e = t1v + qv[j];
                e = fmaxf(e, 0.2f * e);        // leaky_relu (scaled by log2e, scale>0 commutes)
                af[j] = f2bf(exp2f(e));
            }
            dacc[mt] = __builtin_amdgcn_mfma_f32_16x16x32_bf16(af, onesB, dacc[mt], 0, 0, 0);
#pragma unroll
            for (int nt = 0; nt < 4; ++nt)
                acc[mt][nt] = __builtin_amdgcn_mfma_f32_16x16x32_bf16(af, bq[nt], acc[mt][nt], 0, 0, 0);
        }
    }

    // denominators: col0 of dacc holds row sums
#pragma unroll
    for (int mt = 0; mt < 2; ++mt) {
        if (ll == 0) {
#pragma unroll
            for (int reg = 0; reg < 4; ++reg)
                dls[rowbase + mt * 16 + lg * 4 + reg] = dacc[mt][reg];
        }
    }
    __syncthreads();

    // epilogue: scale by 1/d, write hp (B,N,512) fp32
    float* hpb = hp + (b * N_ + n0) * F1_ + h * HID_;
#pragma unroll
    for (int mt = 0; mt < 2; ++mt) {
#pragma unroll
        for (int reg = 0; reg < 4; ++reg) {
            const int row = rowbase + mt * 16 + lg * 4 + reg;
            const float inv = 1.0f / dls[row];
#pragma unroll
            for (int nt = 0; nt < 4; ++nt)
                hpb[row * F1_ + nt * 16 + ll] = acc[mt][nt][reg] * inv;
        }
    }
}

// ---------------- output projection: out = hp @ proj_w + proj_b ----------------
__global__ __launch_bounds__(256) void k_proj(const float* __restrict__ hin,
                                              const float* __restrict__ W,
                                              const float* __restrict__ bias,
                                              float* __restrict__ out) {
    __shared__ __align__(16) float hs[16 * F1_];
    const int n0 = blockIdx.x * 16;  // rows over B*N
    const float4* hb = (const float4*)(hin + n0 * F1_);
    float4* hs4 = (float4*)hs;
    for (int i = threadIdx.x; i < 16 * F1_ / 4; i += 256) hs4[i] = hb[i];
    __syncthreads();

    const int o = threadIdx.x & 127;
    const int ng = threadIdx.x >> 7;  // 0..1
    float acc[8] = {0.f, 0.f, 0.f, 0.f, 0.f, 0.f, 0.f, 0.f};
    for (int f = 0; f < F1_; f += 4) {
        float wv0 = W[(f + 0) * EMB_ + o];
        float wv1 = W[(f + 1) * EMB_ + o];
        float wv2 = W[(f + 2) * EMB_ + o];
        float wv3 = W[(f + 3) * EMB_ + o];
#pragma unroll
        for (int k = 0; k < 8; ++k) {
            float4 hv = *(const float4*)&hs[(ng + 2 * k) * F1_ + f];
            float t = acc[k];
            t = fmaf(hv.x, wv0, t);
            t = fmaf(hv.y, wv1, t);
            t = fmaf(hv.z, wv2, t);
            t = fmaf(hv.w, wv3, t);
            acc[k] = t;
        }
    }
    const float bv = bias[o];
#pragma unroll
    for (int k = 0; k < 8; ++k) out[(n0 + ng + 2 * k) * EMB_ + o] = acc[k] + bv;
}

extern "C" void kernel_launch(void* const* d_in, const int* in_sizes, int n_in,
                              void* d_out, int out_size, void* d_ws, size_t ws_size,
                              hipStream_t stream) {
    const float* x    = (const float*)d_in[0];
    const float* ip_w = (const float*)d_in[1];
    const float* ip_b = (const float*)d_in[2];
    const float* gw0  = (const float*)d_in[3];
    const float* ga0  = (const float*)d_in[4];
    const float* gw1  = (const float*)d_in[5];
    const float* ga1  = (const float*)d_in[6];
    const float* pw   = (const float*)d_in[7];
    const float* pb   = (const float*)d_in[8];
    float* out = (float*)d_out;

    float* ws = (float*)d_ws;
    float* h0 = ws;                                 // 786432 f
    ushort* Whf = (ushort*)(h0 + B_ * N_ * HID_);   // 6291456 ushorts (12 MB)
    float* s1 = (float*)(Whf + B_ * NH_ * (N_ / 32) * 2048);
    float* s2 = s1 + B_ * NH_ * N_;
    float* hp = s2 + B_ * NH_ * N_;                 // 6291456 f

    const int wh_blocks = B_ * NH_ * (N_ / 32);     // 3072
    const int attn_blocks = B_ * NH_ * (N_ / 128);  // 768

    k_inproj<<<B_ * N_ * HID_ / 256, 256, 0, stream>>>(x, ip_w, ip_b, h0);
    k_wh<HID_><<<wh_blocks, 256, 0, stream>>>(h0, gw0, ga0, Whf, s1, s2);
    k_attn<<<attn_blocks, 256, 0, stream>>>(Whf, s1, s2, hp);
    k_wh<F1_><<<wh_blocks, 256, 0, stream>>>(hp, gw1, ga1, Whf, s1, s2);
    k_attn<<<attn_blocks, 256, 0, stream>>>(Whf, s1, s2, hp);
    k_proj<<<(B_ * N_) / 16, 256, 0, stream>>>(hp, pw, pb, out);
}

// Round 4
// 191.250 us; speedup vs baseline: 4.1409x; 2.3206x over previous
//
#include <hip/hip_runtime.h>
#include <hip/hip_bf16.h>

// GAT encoder: B=16, N=768, IN=16, HID=64, HEADS=8, EMB=128, 2 GAT layers.
// Round 3: fix k_wh2 transpose buffer (round 2's swizzle aliased columns and
// overflowed the per-wave buffer). Padded column-major [64][40] stride-80B,
// no swizzle. Everything else identical to round 2.
//
// ws: h0 f[786432] | Whf us[6291456] | s1 f[98304] | s2 f[98304]
//     | hpA us[6291456] | W1f us[262144] | pwf us[65536]

#define B_ 16
#define N_ 768
#define IN_DIM_ 16
#define HID_ 64
#define EMB_ 128
#define NH_ 8
#define F1_ (NH_ * HID_) // 512
#define LOG2E_ 1.4426950408889634f

typedef __attribute__((ext_vector_type(4))) float f32x4;
typedef __attribute__((ext_vector_type(8))) short bf16x8;

static __device__ __forceinline__ short f2bf(float x) {
    __hip_bfloat16 b = __float2bfloat16(x);
    return *reinterpret_cast<short*>(&b);
}

// ---------------- input projection: h0 = x @ ip_w + ip_b ----------------
__global__ __launch_bounds__(256) void k_inproj(const float* __restrict__ x,
                                                const float* __restrict__ w,
                                                const float* __restrict__ bias,
                                                float* __restrict__ h0) {
    int g = blockIdx.x * 256 + threadIdx.x;
    int o = g & (HID_ - 1);
    int row = g >> 6;
    const float* xr = x + row * IN_DIM_;
    float acc = bias[o];
#pragma unroll
    for (int f = 0; f < IN_DIM_; ++f) acc = fmaf(xr[f], w[f * HID_ + o], acc);
    h0[row * HID_ + o] = acc;
}

// ------- convert gat_w1 and proj_w to bf16 B-fragment layout -------
// W1f[h][kt16][nt4][lane][8] = w1[h][kt*32+(l>>4)*8+j][nt*16+(l&15)]
// pwf[kt16][nt8][lane][8]    = pw[kt*32+(l>>4)*8+j][nt*16+(l&15)]
__global__ __launch_bounds__(256) void k_cvtw(const float* __restrict__ w1,
                                              const float* __restrict__ pw,
                                              ushort* __restrict__ W1f,
                                              ushort* __restrict__ pwf) {
    int t = blockIdx.x * 256 + threadIdx.x;  // 40960 total
    if (t < 32768) {
        int lane = t & 63, nt = (t >> 6) & 3, kt = (t >> 8) & 15, h = t >> 12;
        int k0 = kt * 32 + (lane >> 4) * 8;
        int col = nt * 16 + (lane & 15);
        const float* src = w1 + (h * 512 + k0) * 64 + col;
        bf16x8 v;
#pragma unroll
        for (int j = 0; j < 8; ++j) v[j] = f2bf(src[j * 64]);
        *(bf16x8*)&W1f[t * 8] = v;
    } else {
        int u = t - 32768;  // < 8192
        int lane = u & 63, nt = (u >> 6) & 7, kt = u >> 9;
        int k0 = kt * 32 + (lane >> 4) * 8;
        int col = nt * 16 + (lane & 15);
        const float* src = pw + k0 * 128 + col;
        bf16x8 v;
#pragma unroll
        for (int j = 0; j < 8; ++j) v[j] = f2bf(src[j * 128]);
        *(bf16x8*)&pwf[u * 8] = v;
    }
}

// -------- layer-0 Wh GEMM (VALU, K=64) + fused s1/s2 + bf16 B-fragment output --------
template <int F>
__global__ __launch_bounds__(256) void k_wh(const float* __restrict__ hin,
                                            const float* __restrict__ W,
                                            const float* __restrict__ a,
                                            ushort* __restrict__ Whf,
                                            float* __restrict__ s1,
                                            float* __restrict__ s2) {
    __shared__ __align__(16) float hs[32 * F];
    __shared__ __align__(16) ushort fb[2048];
    const int bid = blockIdx.x;
    const int kt = bid % (N_ / 32);
    const int h = (bid / (N_ / 32)) % NH_;
    const int b = bid / ((N_ / 32) * NH_);
    const int n0 = kt * 32;

    const float4* hb = (const float4*)(hin + (b * N_ + n0) * F);
    float4* hs4 = (float4*)hs;
    for (int i = threadIdx.x; i < 32 * F / 4; i += 256) hs4[i] = hb[i];
    __syncthreads();

    const int o = threadIdx.x & 63;
    const int ng = threadIdx.x >> 6;
    float acc[8] = {0.f, 0.f, 0.f, 0.f, 0.f, 0.f, 0.f, 0.f};
    const float* Wp = W + h * F * HID_ + o;
#pragma unroll 4
    for (int f = 0; f < F; f += 4) {
        float wv0 = Wp[(f + 0) * HID_];
        float wv1 = Wp[(f + 1) * HID_];
        float wv2 = Wp[(f + 2) * HID_];
        float wv3 = Wp[(f + 3) * HID_];
#pragma unroll
        for (int k = 0; k < 8; ++k) {
            float4 hv = *(const float4*)&hs[(ng * 8 + k) * F + f];
            float t = acc[k];
            t = fmaf(hv.x, wv0, t);
            t = fmaf(hv.y, wv1, t);
            t = fmaf(hv.z, wv2, t);
            t = fmaf(hv.w, wv3, t);
            acc[k] = t;
        }
    }

    const float a1v = a[h * 2 * HID_ + o];
    const float a2v = a[h * 2 * HID_ + HID_ + o];
    float* s1b = s1 + (b * NH_ + h) * N_ + n0;
    float* s2b = s2 + (b * NH_ + h) * N_ + n0;
#pragma unroll
    for (int k = 0; k < 8; ++k) {
        float r1 = acc[k] * a1v;
        float r2 = acc[k] * a2v;
#pragma unroll
        for (int off = 32; off; off >>= 1) {
            r1 += __shfl_xor(r1, off);
            r2 += __shfl_xor(r2, off);
        }
        if (o == 0) {
            s1b[ng * 8 + k] = r1;
            s2b[ng * 8 + k] = r2;
        }
    }

    bf16x8 pk;
#pragma unroll
    for (int k = 0; k < 8; ++k) pk[k] = f2bf(acc[k]);
    *(bf16x8*)&fb[(((o >> 4) * 64) + ng * 16 + (o & 15)) * 8] = pk;
    __syncthreads();

    bf16x8 v = *(const bf16x8*)&fb[threadIdx.x * 8];
    *(bf16x8*)&Whf[((b * NH_ + h) * (N_ / 32) + kt) * 2048 + threadIdx.x * 8] = v;
}

// ---- fused attention on MFMA; epilogue emits bf16 A-fragments (hpA) ----
// hpA[rtg 0..767][kc 0..15][lane][8]; value = hp[rtg*16+(l&15)][kc*32+(l>>4)*8+j]
__global__ __launch_bounds__(256) void k_attn(const ushort* __restrict__ Whf,
                                              const float* __restrict__ s1,
                                              const float* __restrict__ s2,
                                              ushort* __restrict__ hpA) {
    __shared__ __align__(16) float t1s[128];
    __shared__ __align__(16) float t2s[N_];
    __shared__ __align__(16) float dls[128];
    __shared__ __align__(16) ushort hbuf[128 * 64];  // swizzled [row][col]
    const int bid = blockIdx.x;
    const int nc = bid % (N_ / 128);
    const int h = (bid / (N_ / 128)) % NH_;
    const int b = bid / ((N_ / 128) * NH_);
    const int n0 = nc * 128;
    const int bh = b * NH_ + h;

    const float* s1g = s1 + bh * N_;
    const float* s2g = s2 + bh * N_;
    for (int i = threadIdx.x; i < N_; i += 256) t2s[i] = s2g[i] * LOG2E_;
    if (threadIdx.x < 128) t1s[threadIdx.x] = s1g[n0 + threadIdx.x] * LOG2E_;
    __syncthreads();

    const int lane = threadIdx.x & 63;
    const int w = threadIdx.x >> 6;
    const int rowbase = w * 32;
    const int lg = lane >> 4;
    const int ll = lane & 15;

    const float t1a = t1s[rowbase + ll];
    const float t1b = t1s[rowbase + 16 + ll];

    f32x4 zero4 = {0.f, 0.f, 0.f, 0.f};
    f32x4 acc[2][4];
    f32x4 dacc[2];
#pragma unroll
    for (int mt = 0; mt < 2; ++mt) {
        dacc[mt] = zero4;
#pragma unroll
        for (int nt = 0; nt < 4; ++nt) acc[mt][nt] = zero4;
    }

    bf16x8 onesB;
#pragma unroll
    for (int j = 0; j < 8; ++j) onesB[j] = (ll == 0) ? (short)0x3F80 : (short)0;

    const ushort* Wbase = Whf + bh * ((N_ / 32) * 2048);

    for (int ktile = 0; ktile < N_ / 32; ++ktile) {
        bf16x8 bq[4];
        const ushort* p = Wbase + ktile * 2048 + lane * 8;
#pragma unroll
        for (int nt = 0; nt < 4; ++nt) bq[nt] = *(const bf16x8*)(p + nt * 512);

        float qv[8];
        const float* q = &t2s[ktile * 32 + lg * 8];
#pragma unroll
        for (int j = 0; j < 8; ++j) qv[j] = q[j];

#pragma unroll
        for (int mt = 0; mt < 2; ++mt) {
            const float t1v = mt ? t1b : t1a;
            bf16x8 af;
#pragma unroll
            for (int j = 0; j < 8; ++j) {
                float e = t1v + qv[j];
                e = fmaxf(e, 0.2f * e);
                af[j] = f2bf(exp2f(e));
            }
            dacc[mt] = __builtin_amdgcn_mfma_f32_16x16x32_bf16(af, onesB, dacc[mt], 0, 0, 0);
#pragma unroll
            for (int nt = 0; nt < 4; ++nt)
                acc[mt][nt] = __builtin_amdgcn_mfma_f32_16x16x32_bf16(af, bq[nt], acc[mt][nt], 0, 0, 0);
        }
    }

#pragma unroll
    for (int mt = 0; mt < 2; ++mt) {
        if (ll == 0) {
#pragma unroll
            for (int reg = 0; reg < 4; ++reg)
                dls[rowbase + mt * 16 + lg * 4 + reg] = dacc[mt][reg];
        }
    }
    __syncthreads();

    // scale + swizzled bf16 store to LDS (row stride 128B, swz<128: bijective)
    char* hb8 = (char*)hbuf;
#pragma unroll
    for (int mt = 0; mt < 2; ++mt) {
#pragma unroll
        for (int reg = 0; reg < 4; ++reg) {
            const int row = rowbase + mt * 16 + lg * 4 + reg;
            const float inv = 1.0f / dls[row];
            const int swz = (row & 7) << 4;
#pragma unroll
            for (int nt = 0; nt < 4; ++nt) {
                int c = nt * 16 + ll;
                *(ushort*)(hb8 + row * 128 + ((c * 2) ^ swz)) =
                    (ushort)f2bf(acc[mt][nt][reg] * inv);
            }
        }
    }
    __syncthreads();

    // fragment read + coalesced global store
#pragma unroll
    for (int rt2 = 0; rt2 < 2; ++rt2) {
#pragma unroll
        for (int kc = 0; kc < 2; ++kc) {
            const int rtl = w * 2 + rt2;
            const int row = rtl * 16 + ll;
            bf16x8 v = *(const bf16x8*)(hb8 + row * 128 +
                                        (((kc * 64 + lg * 16)) ^ ((row & 7) << 4)));
            const int rtg = b * 48 + nc * 8 + rtl;
            *(bf16x8*)&hpA[((rtg * 16) + (h * 2 + kc)) * 512 + lane * 8] = v;
        }
    }
}

// -------- layer-1 Wh GEMM on MFMA (768x64x512 per (b,h)) + s1/s2 + Whf frags --------
// Transpose buffer: per-wave [64 cols][40 ushorts] (32 data + 8 pad), stride 80 B,
// 16-byte aligned reads, no swizzle (padding gives <=2-way bank aliasing).
#define TBSTRIDE 40
__global__ __launch_bounds__(256) void k_wh2(const ushort* __restrict__ hpA,
                                             const ushort* __restrict__ W1f,
                                             const float* __restrict__ a,
                                             ushort* __restrict__ Whf,
                                             float* __restrict__ s1,
                                             float* __restrict__ s2) {
    __shared__ __align__(16) ushort tb[4][64 * TBSTRIDE];
    const int bid = blockIdx.x;
    const int chunk = bid % 6;          // 128 rows each
    const int h = (bid / 6) % NH_;
    const int b = bid / (6 * NH_);
    const int bh = b * NH_ + h;

    const int lane = threadIdx.x & 63;
    const int w = threadIdx.x >> 6;
    const int lg = lane >> 4;
    const int ll = lane & 15;

    f32x4 zero4 = {0.f, 0.f, 0.f, 0.f};
    f32x4 acc[2][4];
#pragma unroll
    for (int mt = 0; mt < 2; ++mt)
#pragma unroll
        for (int nt = 0; nt < 4; ++nt) acc[mt][nt] = zero4;

    const int rt0 = b * 48 + chunk * 8 + w * 2;   // global 16-row tile index
    for (int kt = 0; kt < 16; ++kt) {
        bf16x8 afr[2];
#pragma unroll
        for (int mt = 0; mt < 2; ++mt)
            afr[mt] = *(const bf16x8*)&hpA[(((rt0 + mt) * 16) + kt) * 512 + lane * 8];
        bf16x8 bfr[4];
#pragma unroll
        for (int nt = 0; nt < 4; ++nt)
            bfr[nt] = *(const bf16x8*)&W1f[(((h * 16 + kt) * 4) + nt) * 512 + lane * 8];
#pragma unroll
        for (int mt = 0; mt < 2; ++mt)
#pragma unroll
            for (int nt = 0; nt < 4; ++nt)
                acc[mt][nt] = __builtin_amdgcn_mfma_f32_16x16x32_bf16(afr[mt], bfr[nt], acc[mt][nt], 0, 0, 0);
    }

    // fused s1/s2
    float a1v[4], a2v[4];
#pragma unroll
    for (int nt = 0; nt < 4; ++nt) {
        a1v[nt] = a[h * 2 * HID_ + nt * 16 + ll];
        a2v[nt] = a[h * 2 * HID_ + HID_ + nt * 16 + ll];
    }
    const int n0 = chunk * 128;
    float* s1b = s1 + bh * N_ + n0 + w * 32;
    float* s2b = s2 + bh * N_ + n0 + w * 32;
    ushort* tbw = tb[w];
#pragma unroll
    for (int mt = 0; mt < 2; ++mt) {
#pragma unroll
        for (int reg = 0; reg < 4; ++reg) {
            const int r32 = mt * 16 + lg * 4 + reg;
            float p1 = 0.f, p2 = 0.f;
#pragma unroll
            for (int nt = 0; nt < 4; ++nt) {
                float v = acc[mt][nt][reg];
                p1 = fmaf(v, a1v[nt], p1);
                p2 = fmaf(v, a2v[nt], p2);
            }
#pragma unroll
            for (int off = 8; off; off >>= 1) {
                p1 += __shfl_xor(p1, off);
                p2 += __shfl_xor(p2, off);
            }
            if (ll == 0) {
                s1b[r32] = p1;
                s2b[r32] = p2;
            }
            // transposed store: col c = nt*16+ll, row r32
#pragma unroll
            for (int nt = 0; nt < 4; ++nt) {
                int c = nt * 16 + ll;
                tbw[c * TBSTRIDE + r32] = (ushort)f2bf(acc[mt][nt][reg]);
            }
        }
    }
    __syncthreads();

    // B-fragment read (16B: rows lg*8..lg*8+8 of col c) + store
    const int kt2 = chunk * 4 + w;
#pragma unroll
    for (int nt = 0; nt < 4; ++nt) {
        int c = nt * 16 + ll;
        bf16x8 v = *(const bf16x8*)&tbw[c * TBSTRIDE + lg * 8];
        *(bf16x8*)&Whf[(bh * 24 + kt2) * 2048 + nt * 512 + lane * 8] = v;
    }
}

// -------- output projection on MFMA: out = hpA @ pwf + pb --------
__global__ __launch_bounds__(256) void k_projm(const ushort* __restrict__ hpA,
                                               const ushort* __restrict__ pwf,
                                               const float* __restrict__ bias,
                                               float* __restrict__ out) {
    const int blk = blockIdx.x;          // 192 blocks, 64 rows each
    const int lane = threadIdx.x & 63;
    const int w = threadIdx.x >> 6;
    const int wrow = w >> 1, wcol = w & 1;
    const int lg = lane >> 4;
    const int ll = lane & 15;

    f32x4 zero4 = {0.f, 0.f, 0.f, 0.f};
    f32x4 acc[2][4];
#pragma unroll
    for (int mt = 0; mt < 2; ++mt)
#pragma unroll
        for (int nt = 0; nt < 4; ++nt) acc[mt][nt] = zero4;

    const int rt0 = blk * 4 + wrow * 2;
    for (int kt = 0; kt < 16; ++kt) {
        bf16x8 afr[2];
#pragma unroll
        for (int mt = 0; mt < 2; ++mt)
            afr[mt] = *(const bf16x8*)&hpA[(((rt0 + mt) * 16) + kt) * 512 + lane * 8];
        bf16x8 bfr[4];
#pragma unroll
        for (int nt = 0; nt < 4; ++nt)
            bfr[nt] = *(const bf16x8*)&pwf[((kt * 8) + wcol * 4 + nt) * 512 + lane * 8];
#pragma unroll
        for (int mt = 0; mt < 2; ++mt)
#pragma unroll
            for (int nt = 0; nt < 4; ++nt)
                acc[mt][nt] = __builtin_amdgcn_mfma_f32_16x16x32_bf16(afr[mt], bfr[nt], acc[mt][nt], 0, 0, 0);
    }

#pragma unroll
    for (int mt = 0; mt < 2; ++mt) {
#pragma unroll
        for (int reg = 0; reg < 4; ++reg) {
            const int row = blk * 64 + wrow * 32 + mt * 16 + lg * 4 + reg;
#pragma unroll
            for (int nt = 0; nt < 4; ++nt) {
                const int col = wcol * 64 + nt * 16 + ll;
                out[row * EMB_ + col] = acc[mt][nt][reg] + bias[col];
            }
        }
    }
}

extern "C" void kernel_launch(void* const* d_in, const int* in_sizes, int n_in,
                              void* d_out, int out_size, void* d_ws, size_t ws_size,
                              hipStream_t stream) {
    const float* x    = (const float*)d_in[0];
    const float* ip_w = (const float*)d_in[1];
    const float* ip_b = (const float*)d_in[2];
    const float* gw0  = (const float*)d_in[3];
    const float* ga0  = (const float*)d_in[4];
    const float* gw1  = (const float*)d_in[5];
    const float* ga1  = (const float*)d_in[6];
    const float* pw   = (const float*)d_in[7];
    const float* pb   = (const float*)d_in[8];
    float* out = (float*)d_out;

    float* ws = (float*)d_ws;
    float* h0 = ws;                                   // 786432 f
    ushort* Whf = (ushort*)(h0 + B_ * N_ * HID_);     // 6291456 us
    float* s1 = (float*)(Whf + 6291456);              // 98304 f
    float* s2 = s1 + B_ * NH_ * N_;                   // 98304 f
    ushort* hpA = (ushort*)(s2 + B_ * NH_ * N_);      // 6291456 us
    ushort* W1f = hpA + 6291456;                      // 262144 us
    ushort* pwf = W1f + 262144;                       // 65536 us

    const int wh_blocks = B_ * NH_ * (N_ / 32);       // 3072
    const int attn_blocks = B_ * NH_ * (N_ / 128);    // 768

    k_cvtw<<<160, 256, 0, stream>>>(gw1, pw, W1f, pwf);
    k_inproj<<<B_ * N_ * HID_ / 256, 256, 0, stream>>>(x, ip_w, ip_b, h0);
    k_wh<HID_><<<wh_blocks, 256, 0, stream>>>(h0, gw0, ga0, Whf, s1, s2);
    k_attn<<<attn_blocks, 256, 0, stream>>>(Whf, s1, s2, hpA);
    k_wh2<<<B_ * NH_ * 6, 256, 0, stream>>>(hpA, W1f, ga1, Whf, s1, s2);
    k_attn<<<attn_blocks, 256, 0, stream>>>(Whf, s1, s2, hpA);
    k_projm<<<(B_ * N_) / 64, 256, 0, stream>>>(hpA, pwf, pb, out);
}

// Round 5
// 171.625 us; speedup vs baseline: 4.6144x; 1.1143x over previous
//
#include <hip/hip_runtime.h>
#include <hip/hip_bf16.h>

// GAT encoder: B=16, N=768, IN=16, HID=64, HEADS=8, EMB=128, 2 GAT layers.
// Round 5: all GEMMs on MFMA. Input projection fused into a fragment-producer
// (k_h0frag); layer-0 Wh GEMM is now k_wh1m (clone of verified k_wh2, K=64).
// k_projm re-gridded to 384 blocks. k_attn / k_wh2 unchanged from round 3.
//
// ws: h0A us[786432] | Whf us[6291456] | s1 f[98304] | s2 f[98304]
//     | hpA us[6291456] | W1f us[262144] | pwf us[65536] | W0f us[32768]

#define B_ 16
#define N_ 768
#define IN_DIM_ 16
#define HID_ 64
#define EMB_ 128
#define NH_ 8
#define F1_ (NH_ * HID_) // 512
#define LOG2E_ 1.4426950408889634f

typedef __attribute__((ext_vector_type(4))) float f32x4;
typedef __attribute__((ext_vector_type(8))) short bf16x8;

static __device__ __forceinline__ short f2bf(float x) {
    __hip_bfloat16 b = __float2bfloat16(x);
    return *reinterpret_cast<short*>(&b);
}

// ---- input projection emitting bf16 A-fragments directly ----
// h0A[rtg][kt][lane][8]: value h0[rtg*16+(l&15)][kt*32+(l>>4)*8+j]
__global__ __launch_bounds__(256) void k_h0frag(const float* __restrict__ x,
                                                const float* __restrict__ w,
                                                const float* __restrict__ bias,
                                                ushort* __restrict__ h0A) {
    const int t = blockIdx.x * 256 + threadIdx.x;  // 98304 threads
    const int lane = t & 63;
    const int kt = (t >> 6) & 1;
    const int rtg = t >> 7;
    const int row = rtg * 16 + (lane & 15);
    const int k0 = kt * 32 + (lane >> 4) * 8;
    const float* xr = x + row * IN_DIM_;
    float xv[IN_DIM_];
#pragma unroll
    for (int f = 0; f < IN_DIM_; ++f) xv[f] = xr[f];
    bf16x8 v;
#pragma unroll
    for (int j = 0; j < 8; ++j) {
        float acc = bias[k0 + j];
#pragma unroll
        for (int f = 0; f < IN_DIM_; ++f) acc = fmaf(xv[f], w[f * HID_ + k0 + j], acc);
        v[j] = f2bf(acc);
    }
    *(bf16x8*)&h0A[t * 8] = v;  // flat: ((rtg*2+kt)*64+lane)*8
}

// ------- convert gat_w1, proj_w, gat_w0 to bf16 B-fragment layout -------
// W1f[h][kt16][nt4][lane][8] = w1[h][kt*32+(l>>4)*8+j][nt*16+(l&15)]
// pwf[kt16][nt8][lane][8]    = pw[kt*32+(l>>4)*8+j][nt*16+(l&15)]
// W0f[h][kt2][nt4][lane][8]  = w0[h][kt*32+(l>>4)*8+j][nt*16+(l&15)]
__global__ __launch_bounds__(256) void k_cvtw(const float* __restrict__ w1,
                                              const float* __restrict__ pw,
                                              const float* __restrict__ w0,
                                              ushort* __restrict__ W1f,
                                              ushort* __restrict__ pwf,
                                              ushort* __restrict__ W0f) {
    int t = blockIdx.x * 256 + threadIdx.x;  // 45056 total
    if (t < 32768) {
        int lane = t & 63, nt = (t >> 6) & 3, kt = (t >> 8) & 15, h = t >> 12;
        int k0 = kt * 32 + (lane >> 4) * 8;
        int col = nt * 16 + (lane & 15);
        const float* src = w1 + (h * 512 + k0) * 64 + col;
        bf16x8 v;
#pragma unroll
        for (int j = 0; j < 8; ++j) v[j] = f2bf(src[j * 64]);
        *(bf16x8*)&W1f[t * 8] = v;
    } else if (t < 40960) {
        int u = t - 32768;  // < 8192
        int lane = u & 63, nt = (u >> 6) & 7, kt = u >> 9;
        int k0 = kt * 32 + (lane >> 4) * 8;
        int col = nt * 16 + (lane & 15);
        const float* src = pw + k0 * 128 + col;
        bf16x8 v;
#pragma unroll
        for (int j = 0; j < 8; ++j) v[j] = f2bf(src[j * 128]);
        *(bf16x8*)&pwf[u * 8] = v;
    } else {
        int u = t - 40960;  // < 4096
        int lane = u & 63, nt = (u >> 6) & 3, kt = (u >> 8) & 1, h = u >> 9;
        int k0 = kt * 32 + (lane >> 4) * 8;
        int col = nt * 16 + (lane & 15);
        const float* src = w0 + (h * 64 + k0) * 64 + col;
        bf16x8 v;
#pragma unroll
        for (int j = 0; j < 8; ++j) v[j] = f2bf(src[j * 64]);
        *(bf16x8*)&W0f[u * 8] = v;
    }
}

#define TBSTRIDE 40

// -------- layer-0 Wh GEMM on MFMA (K=64) + fused s1/s2 + Whf B-frags --------
// Structure cloned from verified k_wh2; kt loop is 2 instead of 16.
__global__ __launch_bounds__(256) void k_wh1m(const ushort* __restrict__ h0A,
                                              const ushort* __restrict__ W0f,
                                              const float* __restrict__ a,
                                              ushort* __restrict__ Whf,
                                              float* __restrict__ s1,
                                              float* __restrict__ s2) {
    __shared__ __align__(16) ushort tb[4][64 * TBSTRIDE];
    const int bid = blockIdx.x;
    const int chunk = bid % 6;          // 128 rows each
    const int h = (bid / 6) % NH_;
    const int b = bid / (6 * NH_);
    const int bh = b * NH_ + h;

    const int lane = threadIdx.x & 63;
    const int w = threadIdx.x >> 6;
    const int lg = lane >> 4;
    const int ll = lane & 15;

    f32x4 zero4 = {0.f, 0.f, 0.f, 0.f};
    f32x4 acc[2][4];
#pragma unroll
    for (int mt = 0; mt < 2; ++mt)
#pragma unroll
        for (int nt = 0; nt < 4; ++nt) acc[mt][nt] = zero4;

    const int rt0 = b * 48 + chunk * 8 + w * 2;
#pragma unroll
    for (int kt = 0; kt < 2; ++kt) {
        bf16x8 afr[2];
#pragma unroll
        for (int mt = 0; mt < 2; ++mt)
            afr[mt] = *(const bf16x8*)&h0A[(((rt0 + mt) * 2) + kt) * 512 + lane * 8];
        bf16x8 bfr[4];
#pragma unroll
        for (int nt = 0; nt < 4; ++nt)
            bfr[nt] = *(const bf16x8*)&W0f[(((h * 2 + kt) * 4) + nt) * 512 + lane * 8];
#pragma unroll
        for (int mt = 0; mt < 2; ++mt)
#pragma unroll
            for (int nt = 0; nt < 4; ++nt)
                acc[mt][nt] = __builtin_amdgcn_mfma_f32_16x16x32_bf16(afr[mt], bfr[nt], acc[mt][nt], 0, 0, 0);
    }

    float a1v[4], a2v[4];
#pragma unroll
    for (int nt = 0; nt < 4; ++nt) {
        a1v[nt] = a[h * 2 * HID_ + nt * 16 + ll];
        a2v[nt] = a[h * 2 * HID_ + HID_ + nt * 16 + ll];
    }
    const int n0 = chunk * 128;
    float* s1b = s1 + bh * N_ + n0 + w * 32;
    float* s2b = s2 + bh * N_ + n0 + w * 32;
    ushort* tbw = tb[w];
#pragma unroll
    for (int mt = 0; mt < 2; ++mt) {
#pragma unroll
        for (int reg = 0; reg < 4; ++reg) {
            const int r32 = mt * 16 + lg * 4 + reg;
            float p1 = 0.f, p2 = 0.f;
#pragma unroll
            for (int nt = 0; nt < 4; ++nt) {
                float v = acc[mt][nt][reg];
                p1 = fmaf(v, a1v[nt], p1);
                p2 = fmaf(v, a2v[nt], p2);
            }
#pragma unroll
            for (int off = 8; off; off >>= 1) {
                p1 += __shfl_xor(p1, off);
                p2 += __shfl_xor(p2, off);
            }
            if (ll == 0) {
                s1b[r32] = p1;
                s2b[r32] = p2;
            }
#pragma unroll
            for (int nt = 0; nt < 4; ++nt) {
                int c = nt * 16 + ll;
                tbw[c * TBSTRIDE + r32] = (ushort)f2bf(acc[mt][nt][reg]);
            }
        }
    }
    __syncthreads();

    const int kt2 = chunk * 4 + w;
#pragma unroll
    for (int nt = 0; nt < 4; ++nt) {
        int c = nt * 16 + ll;
        bf16x8 v = *(const bf16x8*)&tbw[c * TBSTRIDE + lg * 8];
        *(bf16x8*)&Whf[(bh * 24 + kt2) * 2048 + nt * 512 + lane * 8] = v;
    }
}

// ---- fused attention on MFMA; epilogue emits bf16 A-fragments (hpA) ----
// hpA[rtg 0..767][kc 0..15][lane][8]; value = hp[rtg*16+(l&15)][kc*32+(l>>4)*8+j]
__global__ __launch_bounds__(256) void k_attn(const ushort* __restrict__ Whf,
                                              const float* __restrict__ s1,
                                              const float* __restrict__ s2,
                                              ushort* __restrict__ hpA) {
    __shared__ __align__(16) float t1s[128];
    __shared__ __align__(16) float t2s[N_];
    __shared__ __align__(16) float dls[128];
    __shared__ __align__(16) ushort hbuf[128 * 64];  // swizzled [row][col]
    const int bid = blockIdx.x;
    const int nc = bid % (N_ / 128);
    const int h = (bid / (N_ / 128)) % NH_;
    const int b = bid / ((N_ / 128) * NH_);
    const int n0 = nc * 128;
    const int bh = b * NH_ + h;

    const float* s1g = s1 + bh * N_;
    const float* s2g = s2 + bh * N_;
    for (int i = threadIdx.x; i < N_; i += 256) t2s[i] = s2g[i] * LOG2E_;
    if (threadIdx.x < 128) t1s[threadIdx.x] = s1g[n0 + threadIdx.x] * LOG2E_;
    __syncthreads();

    const int lane = threadIdx.x & 63;
    const int w = threadIdx.x >> 6;
    const int rowbase = w * 32;
    const int lg = lane >> 4;
    const int ll = lane & 15;

    const float t1a = t1s[rowbase + ll];
    const float t1b = t1s[rowbase + 16 + ll];

    f32x4 zero4 = {0.f, 0.f, 0.f, 0.f};
    f32x4 acc[2][4];
    f32x4 dacc[2];
#pragma unroll
    for (int mt = 0; mt < 2; ++mt) {
        dacc[mt] = zero4;
#pragma unroll
        for (int nt = 0; nt < 4; ++nt) acc[mt][nt] = zero4;
    }

    bf16x8 onesB;
#pragma unroll
    for (int j = 0; j < 8; ++j) onesB[j] = (ll == 0) ? (short)0x3F80 : (short)0;

    const ushort* Wbase = Whf + bh * ((N_ / 32) * 2048);

    for (int ktile = 0; ktile < N_ / 32; ++ktile) {
        bf16x8 bq[4];
        const ushort* p = Wbase + ktile * 2048 + lane * 8;
#pragma unroll
        for (int nt = 0; nt < 4; ++nt) bq[nt] = *(const bf16x8*)(p + nt * 512);

        float qv[8];
        const float* q = &t2s[ktile * 32 + lg * 8];
#pragma unroll
        for (int j = 0; j < 8; ++j) qv[j] = q[j];

#pragma unroll
        for (int mt = 0; mt < 2; ++mt) {
            const float t1v = mt ? t1b : t1a;
            bf16x8 af;
#pragma unroll
            for (int j = 0; j < 8; ++j) {
                float e = t1v + qv[j];
                e = fmaxf(e, 0.2f * e);
                af[j] = f2bf(exp2f(e));
            }
            dacc[mt] = __builtin_amdgcn_mfma_f32_16x16x32_bf16(af, onesB, dacc[mt], 0, 0, 0);
#pragma unroll
            for (int nt = 0; nt < 4; ++nt)
                acc[mt][nt] = __builtin_amdgcn_mfma_f32_16x16x32_bf16(af, bq[nt], acc[mt][nt], 0, 0, 0);
        }
    }

#pragma unroll
    for (int mt = 0; mt < 2; ++mt) {
        if (ll == 0) {
#pragma unroll
            for (int reg = 0; reg < 4; ++reg)
                dls[rowbase + mt * 16 + lg * 4 + reg] = dacc[mt][reg];
        }
    }
    __syncthreads();

    // scale + swizzled bf16 store to LDS (row stride 128B, swz<128: bijective)
    char* hb8 = (char*)hbuf;
#pragma unroll
    for (int mt = 0; mt < 2; ++mt) {
#pragma unroll
        for (int reg = 0; reg < 4; ++reg) {
            const int row = rowbase + mt * 16 + lg * 4 + reg;
            const float inv = 1.0f / dls[row];
            const int swz = (row & 7) << 4;
#pragma unroll
            for (int nt = 0; nt < 4; ++nt) {
                int c = nt * 16 + ll;
                *(ushort*)(hb8 + row * 128 + ((c * 2) ^ swz)) =
                    (ushort)f2bf(acc[mt][nt][reg] * inv);
            }
        }
    }
    __syncthreads();

    // fragment read + coalesced global store
#pragma unroll
    for (int rt2 = 0; rt2 < 2; ++rt2) {
#pragma unroll
        for (int kc = 0; kc < 2; ++kc) {
            const int rtl = w * 2 + rt2;
            const int row = rtl * 16 + ll;
            bf16x8 v = *(const bf16x8*)(hb8 + row * 128 +
                                        (((kc * 64 + lg * 16)) ^ ((row & 7) << 4)));
            const int rtg = b * 48 + nc * 8 + rtl;
            *(bf16x8*)&hpA[((rtg * 16) + (h * 2 + kc)) * 512 + lane * 8] = v;
        }
    }
}

// -------- layer-1 Wh GEMM on MFMA (768x64x512 per (b,h)) + s1/s2 + Whf frags --------
__global__ __launch_bounds__(256) void k_wh2(const ushort* __restrict__ hpA,
                                             const ushort* __restrict__ W1f,
                                             const float* __restrict__ a,
                                             ushort* __restrict__ Whf,
                                             float* __restrict__ s1,
                                             float* __restrict__ s2) {
    __shared__ __align__(16) ushort tb[4][64 * TBSTRIDE];
    const int bid = blockIdx.x;
    const int chunk = bid % 6;          // 128 rows each
    const int h = (bid / 6) % NH_;
    const int b = bid / (6 * NH_);
    const int bh = b * NH_ + h;

    const int lane = threadIdx.x & 63;
    const int w = threadIdx.x >> 6;
    const int lg = lane >> 4;
    const int ll = lane & 15;

    f32x4 zero4 = {0.f, 0.f, 0.f, 0.f};
    f32x4 acc[2][4];
#pragma unroll
    for (int mt = 0; mt < 2; ++mt)
#pragma unroll
        for (int nt = 0; nt < 4; ++nt) acc[mt][nt] = zero4;

    const int rt0 = b * 48 + chunk * 8 + w * 2;
    for (int kt = 0; kt < 16; ++kt) {
        bf16x8 afr[2];
#pragma unroll
        for (int mt = 0; mt < 2; ++mt)
            afr[mt] = *(const bf16x8*)&hpA[(((rt0 + mt) * 16) + kt) * 512 + lane * 8];
        bf16x8 bfr[4];
#pragma unroll
        for (int nt = 0; nt < 4; ++nt)
            bfr[nt] = *(const bf16x8*)&W1f[(((h * 16 + kt) * 4) + nt) * 512 + lane * 8];
#pragma unroll
        for (int mt = 0; mt < 2; ++mt)
#pragma unroll
            for (int nt = 0; nt < 4; ++nt)
                acc[mt][nt] = __builtin_amdgcn_mfma_f32_16x16x32_bf16(afr[mt], bfr[nt], acc[mt][nt], 0, 0, 0);
    }

    float a1v[4], a2v[4];
#pragma unroll
    for (int nt = 0; nt < 4; ++nt) {
        a1v[nt] = a[h * 2 * HID_ + nt * 16 + ll];
        a2v[nt] = a[h * 2 * HID_ + HID_ + nt * 16 + ll];
    }
    const int n0 = chunk * 128;
    float* s1b = s1 + bh * N_ + n0 + w * 32;
    float* s2b = s2 + bh * N_ + n0 + w * 32;
    ushort* tbw = tb[w];
#pragma unroll
    for (int mt = 0; mt < 2; ++mt) {
#pragma unroll
        for (int reg = 0; reg < 4; ++reg) {
            const int r32 = mt * 16 + lg * 4 + reg;
            float p1 = 0.f, p2 = 0.f;
#pragma unroll
            for (int nt = 0; nt < 4; ++nt) {
                float v = acc[mt][nt][reg];
                p1 = fmaf(v, a1v[nt], p1);
                p2 = fmaf(v, a2v[nt], p2);
            }
#pragma unroll
            for (int off = 8; off; off >>= 1) {
                p1 += __shfl_xor(p1, off);
                p2 += __shfl_xor(p2, off);
            }
            if (ll == 0) {
                s1b[r32] = p1;
                s2b[r32] = p2;
            }
#pragma unroll
            for (int nt = 0; nt < 4; ++nt) {
                int c = nt * 16 + ll;
                tbw[c * TBSTRIDE + r32] = (ushort)f2bf(acc[mt][nt][reg]);
            }
        }
    }
    __syncthreads();

    const int kt2 = chunk * 4 + w;
#pragma unroll
    for (int nt = 0; nt < 4; ++nt) {
        int c = nt * 16 + ll;
        bf16x8 v = *(const bf16x8*)&tbw[c * TBSTRIDE + lg * 8];
        *(bf16x8*)&Whf[(bh * 24 + kt2) * 2048 + nt * 512 + lane * 8] = v;
    }
}

// -------- output projection on MFMA: out = hpA @ pwf + pb (384 blocks) --------
__global__ __launch_bounds__(256) void k_projm(const ushort* __restrict__ hpA,
                                               const ushort* __restrict__ pwf,
                                               const float* __restrict__ bias,
                                               float* __restrict__ out) {
    const int blk = blockIdx.x;          // 384 blocks, 32 rows each
    const int lane = threadIdx.x & 63;
    const int w = threadIdx.x >> 6;
    const int wrow = w >> 1, wcol = w & 1;
    const int lg = lane >> 4;
    const int ll = lane & 15;

    f32x4 zero4 = {0.f, 0.f, 0.f, 0.f};
    f32x4 acc[4];
#pragma unroll
    for (int nt = 0; nt < 4; ++nt) acc[nt] = zero4;

    const int rt = blk * 2 + wrow;
    for (int kt = 0; kt < 16; ++kt) {
        bf16x8 afr = *(const bf16x8*)&hpA[((rt * 16) + kt) * 512 + lane * 8];
        bf16x8 bfr[4];
#pragma unroll
        for (int nt = 0; nt < 4; ++nt)
            bfr[nt] = *(const bf16x8*)&pwf[((kt * 8) + wcol * 4 + nt) * 512 + lane * 8];
#pragma unroll
        for (int nt = 0; nt < 4; ++nt)
            acc[nt] = __builtin_amdgcn_mfma_f32_16x16x32_bf16(afr, bfr[nt], acc[nt], 0, 0, 0);
    }

#pragma unroll
    for (int reg = 0; reg < 4; ++reg) {
        const int row = blk * 32 + wrow * 16 + lg * 4 + reg;
#pragma unroll
        for (int nt = 0; nt < 4; ++nt) {
            const int col = wcol * 64 + nt * 16 + ll;
            out[row * EMB_ + col] = acc[nt][reg] + bias[col];
        }
    }
}

extern "C" void kernel_launch(void* const* d_in, const int* in_sizes, int n_in,
                              void* d_out, int out_size, void* d_ws, size_t ws_size,
                              hipStream_t stream) {
    const float* x    = (const float*)d_in[0];
    const float* ip_w = (const float*)d_in[1];
    const float* ip_b = (const float*)d_in[2];
    const float* gw0  = (const float*)d_in[3];
    const float* ga0  = (const float*)d_in[4];
    const float* gw1  = (const float*)d_in[5];
    const float* ga1  = (const float*)d_in[6];
    const float* pw   = (const float*)d_in[7];
    const float* pb   = (const float*)d_in[8];
    float* out = (float*)d_out;

    ushort* h0A = (ushort*)d_ws;                      // 786432 us
    ushort* Whf = h0A + 786432;                       // 6291456 us
    float* s1 = (float*)(Whf + 6291456);              // 98304 f
    float* s2 = s1 + B_ * NH_ * N_;                   // 98304 f
    ushort* hpA = (ushort*)(s2 + B_ * NH_ * N_);      // 6291456 us
    ushort* W1f = hpA + 6291456;                      // 262144 us
    ushort* pwf = W1f + 262144;                       // 65536 us
    ushort* W0f = pwf + 65536;                        // 32768 us

    const int attn_blocks = B_ * NH_ * (N_ / 128);    // 768
    const int wh_blocks = B_ * NH_ * 6;               // 768

    k_cvtw<<<176, 256, 0, stream>>>(gw1, pw, gw0, W1f, pwf, W0f);
    k_h0frag<<<384, 256, 0, stream>>>(x, ip_w, ip_b, h0A);
    k_wh1m<<<wh_blocks, 256, 0, stream>>>(h0A, W0f, ga0, Whf, s1, s2);
    k_attn<<<attn_blocks, 256, 0, stream>>>(Whf, s1, s2, hpA);
    k_wh2<<<wh_blocks, 256, 0, stream>>>(hpA, W1f, ga1, Whf, s1, s2);
    k_attn<<<attn_blocks, 256, 0, stream>>>(Whf, s1, s2, hpA);
    k_projm<<<(B_ * N_) / 32, 256, 0, stream>>>(hpA, pwf, pb, out);
}